// Round 1
// baseline (203.648 us; speedup 1.0000x reference)
//
#include <hip/hip_runtime.h>
#include <hip/hip_bf16.h>

#define D_DIM 64
#define K_CODES 512
#define TOK_TILE 64
#define CHUNK 64
#define NCHUNK (K_CODES / CHUNK)
#define XS_STRIDE (TOK_TILE + 4)   // 68 floats = 272 B: keeps float4 reads 16B-aligned, breaks pow2 bank stride

// Prep: ET[k][d] = E[d][k] (transposed codebook for coalesced gather), ee[k] = sum_d E[d][k]^2
__global__ __launch_bounds__(256) void vq_prep_kernel(const float* __restrict__ E,
                                                      float* __restrict__ ee,
                                                      float* __restrict__ ET) {
    int k = blockIdx.x * blockDim.x + threadIdx.x;
    if (k >= K_CODES) return;
    float s = 0.f;
#pragma unroll
    for (int d = 0; d < D_DIM; ++d) {
        float v = E[(size_t)d * K_CODES + k];   // coalesced across k
        ET[(size_t)k * D_DIM + d] = v;
        s = fmaf(v, v, s);
    }
    ee[k] = s;
}

__global__ __launch_bounds__(256, 4) void vq_main_kernel(
        const float* __restrict__ x, const float* __restrict__ E,
        const float* __restrict__ ee_g, const float* __restrict__ ET,
        float* __restrict__ out_q, float* __restrict__ out_loss,
        int use_ws, float loss_scale) {
    __shared__ __align__(16) float Xs[D_DIM][XS_STRIDE];  // [d][token]
    __shared__ __align__(16) float Es[D_DIM][CHUNK];      // [d][code], stride 64 (flat staging)
    __shared__ float ee_s[K_CODES];
    __shared__ int idx_s[TOK_TILE];
    __shared__ float wsum_s[4];

    const int tid = threadIdx.x;
    const int t0 = blockIdx.x * TOK_TILE;
    const int tx = tid & 15;         // code group
    const int ty = tid >> 4;         // token group
    const int ty4 = ty * 4, tx4 = tx * 4;

    // ---- stage X tile transposed: Xs[d][t]. Global reads fully coalesced (contig 1 KiB/wave).
#pragma unroll
    for (int it = 0; it < 4; ++it) {
        int tl = it * 16 + (tid >> 4);
        int d0 = (tid & 15) * 4;
        float4 v = *(const float4*)(x + (size_t)(t0 + tl) * D_DIM + d0);
        Xs[d0 + 0][tl] = v.x;
        Xs[d0 + 1][tl] = v.y;
        Xs[d0 + 2][tl] = v.z;
        Xs[d0 + 3][tl] = v.w;
    }

    // ---- stage code squared-norms
    if (use_ws) {
#pragma unroll
        for (int i = 0; i < K_CODES / 256; ++i) ee_s[i * 256 + tid] = ee_g[i * 256 + tid];
    } else {
        for (int k = tid; k < K_CODES; k += 256) {
            float s = 0.f;
#pragma unroll
            for (int d = 0; d < D_DIM; ++d) {
                float v = E[(size_t)d * K_CODES + k];
                s = fmaf(v, v, s);
            }
            ee_s[k] = s;
        }
    }

    // running argmin over score = ee - 2*dot  (||x||^2 is constant per token)
    float bd[4] = {3.4e38f, 3.4e38f, 3.4e38f, 3.4e38f};
    int bi[4] = {0, 0, 0, 0};

    for (int c = 0; c < NCHUNK; ++c) {
        __syncthreads();   // protect Es (and on c==0, Xs/ee_s) before rewrite
        // ---- stage E chunk: flat contiguous copy -> conflict-free b128 LDS writes,
        //      global reads are 4 contiguous 256B row-segments per instruction.
#pragma unroll
        for (int w = 0; w < 4; ++w) {
            int fidx = w * 256 + tid;          // float4 index in [0,1024)
            int d = fidx >> 4;                 // 16 float4 per 64-float row
            int k0 = (fidx & 15) * 4;
            float4 v = *(const float4*)(E + (size_t)d * K_CODES + c * CHUNK + k0);
            *(float4*)&Es[d][k0] = v;
        }
        __syncthreads();

        float acc[4][4] = {};
#pragma unroll
        for (int d = 0; d < D_DIM; ++d) {
            float4 a = *(const float4*)&Xs[d][ty4];   // 4 tokens at dim d
            float4 b = *(const float4*)&Es[d][tx4];   // 4 codes  at dim d
            acc[0][0] = fmaf(a.x, b.x, acc[0][0]);
            acc[0][1] = fmaf(a.x, b.y, acc[0][1]);
            acc[0][2] = fmaf(a.x, b.z, acc[0][2]);
            acc[0][3] = fmaf(a.x, b.w, acc[0][3]);
            acc[1][0] = fmaf(a.y, b.x, acc[1][0]);
            acc[1][1] = fmaf(a.y, b.y, acc[1][1]);
            acc[1][2] = fmaf(a.y, b.z, acc[1][2]);
            acc[1][3] = fmaf(a.y, b.w, acc[1][3]);
            acc[2][0] = fmaf(a.z, b.x, acc[2][0]);
            acc[2][1] = fmaf(a.z, b.y, acc[2][1]);
            acc[2][2] = fmaf(a.z, b.z, acc[2][2]);
            acc[2][3] = fmaf(a.z, b.w, acc[2][3]);
            acc[3][0] = fmaf(a.w, b.x, acc[3][0]);
            acc[3][1] = fmaf(a.w, b.y, acc[3][1]);
            acc[3][2] = fmaf(a.w, b.z, acc[3][2]);
            acc[3][3] = fmaf(a.w, b.w, acc[3][3]);
        }

        const int kbase = c * CHUNK + tx4;
#pragma unroll
        for (int i = 0; i < 4; ++i) {
#pragma unroll
            for (int j = 0; j < 4; ++j) {
                float s = fmaf(-2.f, acc[i][j], ee_s[kbase + j]);
                // strict < : within a thread code indices are ascending, so ties keep lowest idx
                if (s < bd[i]) { bd[i] = s; bi[i] = kbase + j; }
            }
        }
    }

    // ---- cross-thread argmin over the 16 tx lanes (contiguous lanes, same wave)
#pragma unroll
    for (int mask = 1; mask < 16; mask <<= 1) {
#pragma unroll
        for (int i = 0; i < 4; ++i) {
            float od = __shfl_xor(bd[i], mask);
            int oi = __shfl_xor(bi[i], mask);
            if (od < bd[i] || (od == bd[i] && oi < bi[i])) { bd[i] = od; bi[i] = oi; }
        }
    }
    if (tx == 0) {
#pragma unroll
        for (int i = 0; i < 4; ++i) idx_s[ty4 + i] = bi[i];
    }
    __syncthreads();

    // ---- epilogue: gather q, write out (coalesced float4), loss partial
    const int tok = tid >> 2;        // 64 tokens, 4 threads each
    const int part = tid & 3;
    const int gidx = idx_s[tok];
    const int gt = t0 + tok;
    float lsum = 0.f;
#pragma unroll
    for (int w = 0; w < 4; ++w) {
        int o = part * 16 + w * 4;
        float4 qv;
        if (use_ws) {
            qv = *(const float4*)(ET + (size_t)gidx * D_DIM + o);
        } else {
            qv.x = E[(size_t)(o + 0) * K_CODES + gidx];
            qv.y = E[(size_t)(o + 1) * K_CODES + gidx];
            qv.z = E[(size_t)(o + 2) * K_CODES + gidx];
            qv.w = E[(size_t)(o + 3) * K_CODES + gidx];
        }
        float4 xv;
        xv.x = Xs[o + 0][tok];
        xv.y = Xs[o + 1][tok];
        xv.z = Xs[o + 2][tok];
        xv.w = Xs[o + 3][tok];
        float dx = qv.x - xv.x;
        float dy = qv.y - xv.y;
        float dz = qv.z - xv.z;
        float dw = qv.w - xv.w;
        lsum = fmaf(dx, dx, lsum);
        lsum = fmaf(dy, dy, lsum);
        lsum = fmaf(dz, dz, lsum);
        lsum = fmaf(dw, dw, lsum);
        *(float4*)(out_q + (size_t)gt * D_DIM + o) = qv;
    }

    // ---- block loss reduction: wave shuffle then LDS then one atomic
#pragma unroll
    for (int mask = 1; mask < 64; mask <<= 1) lsum += __shfl_xor(lsum, mask);
    if ((tid & 63) == 0) wsum_s[tid >> 6] = lsum;
    __syncthreads();
    if (tid == 0) {
        float total = wsum_s[0] + wsum_s[1] + wsum_s[2] + wsum_s[3];
        atomicAdd(out_loss, total * loss_scale);
    }
}

extern "C" void kernel_launch(void* const* d_in, const int* in_sizes, int n_in,
                              void* d_out, int out_size, void* d_ws, size_t ws_size,
                              hipStream_t stream) {
    const float* x = (const float*)d_in[0];     // [B,T,D] fp32
    const float* E = (const float*)d_in[1];     // [D,K] fp32
    float* out = (float*)d_out;                 // q flat [N*D] ++ loss [1]
    const int n_tok = in_sizes[0] / D_DIM;      // 131072
    float* loss_ptr = out + (out_size - 1);

    const size_t ws_needed = (size_t)(K_CODES + K_CODES * D_DIM) * sizeof(float);
    const int use_ws = (ws_size >= ws_needed) ? 1 : 0;
    float* ee = (float*)d_ws;
    float* ET = ee + K_CODES;

    hipMemsetAsync(loss_ptr, 0, sizeof(float), stream);
    if (use_ws) {
        vq_prep_kernel<<<(K_CODES + 255) / 256, 256, 0, stream>>>(E, ee, ET);
    }
    const float loss_scale = 2.0f / (float)(n_tok * D_DIM);
    vq_main_kernel<<<n_tok / TOK_TILE, 256, 0, stream>>>(x, E, ee, ET, out, loss_ptr,
                                                         use_ws, loss_scale);
}

// Round 2
// 131.858 us; speedup vs baseline: 1.5444x; 1.5444x over previous
//
#include <hip/hip_runtime.h>
#include <hip/hip_bf16.h>

#define D_DIM 64
#define K_CODES 512

typedef _Float16 half8 __attribute__((ext_vector_type(8)));
typedef float f32x4 __attribute__((ext_vector_type(4)));

// ws layout: ee f32[512] @0 ; ET f32[512*64] @2048 B ; Bimg f16[512*64*2] @133120 B
#define WS_EE_OFF 0
#define WS_ET_OFF 2048
#define WS_BIMG_OFF 133120
#define WS_NEEDED (133120 + 131072)

// ---------------- prep: ee, ET (gather layout), Bimg (frag-ordered f16 hi/lo) ------------
// Bimg element addr (f16 units): ((t*4 + part)*4 + g)*128 + n*8 + j
//   code k = t*16+n ; dim d = ks*32 + g*8 + j ; part: 0,1 = hi ks0/ks1 ; 2,3 = lo ks0/ks1 (lo pre-scaled by 2^11)
__global__ __launch_bounds__(256) void vq3_prep(const float* __restrict__ E,
                                                float* __restrict__ ee,
                                                float* __restrict__ ET,
                                                _Float16* __restrict__ Bimg) {
    int k = blockIdx.x * 256 + threadIdx.x;
    if (k >= K_CODES) return;
    const int t = k >> 4, n = k & 15;
    float s = 0.f;
#pragma unroll
    for (int d = 0; d < D_DIM; ++d) {
        float e = E[(size_t)d * K_CODES + k];
        s = fmaf(e, e, s);
        ET[(size_t)k * D_DIM + d] = e;
        _Float16 hi = (_Float16)e;
        _Float16 lo = (_Float16)((e - (float)hi) * 2048.0f);
        int ks = d >> 5, g = (d >> 3) & 3, j = d & 7;
        size_t base = ((size_t)(t * 4) * 4 + (size_t)g) * 128 + n * 8 + j;
        Bimg[base + (size_t)ks * 512] = hi;          // part = ks     -> +ks*4*128
        Bimg[base + (size_t)(2 + ks) * 512] = lo;    // part = 2+ks
    }
    ee[k] = s;
}

// ---------------- main: 3-pass split-f16 MFMA, B-frags direct from global ------------
__global__ __launch_bounds__(256, 2) void vq3_main(
        const float* __restrict__ x, const float* __restrict__ ee,
        const float* __restrict__ ET, const _Float16* __restrict__ Bimg,
        float* __restrict__ out_q, float* __restrict__ out_loss, float loss_scale) {
    __shared__ int idx_s[256];
    __shared__ float wsum_s[4];

    const int tid = threadIdx.x;
    const int l = tid & 63;            // lane
    const int w = tid >> 6;            // wave in block
    const int g = l >> 4;              // k-group quad (0..3)
    const int n = l & 15;              // A row / B col within tile
    const int bt0 = blockIdx.x * 256;  // block token base
    const int t0 = bt0 + w * 64;       // wave token base (64 tokens/wave)

    // ---- A fragments: 4 row-tiles x 2 k-steps, hi and lo(x2^11), held in regs all kernel
    half8 Ahi[4][2], Alo[4][2];
#pragma unroll
    for (int rt = 0; rt < 4; ++rt) {
#pragma unroll
        for (int ks = 0; ks < 2; ++ks) {
            const float4* xp = (const float4*)(x + (size_t)(t0 + rt * 16 + n) * D_DIM + ks * 32 + g * 8);
            float4 a = xp[0], b = xp[1];
            float va[8] = {a.x, a.y, a.z, a.w, b.x, b.y, b.z, b.w};
            half8 h, lo;
#pragma unroll
            for (int j = 0; j < 8; ++j) {
                _Float16 hj = (_Float16)va[j];
                h[j] = hj;
                lo[j] = (_Float16)((va[j] - (float)hj) * 2048.0f);
            }
            Ahi[rt][ks] = h;
            Alo[rt][ks] = lo;
        }
    }

    // ---- running argmin state: 4 rt x 4 C-rows per lane
    float bd[4][4];
    int bi[4][4];
#pragma unroll
    for (int i = 0; i < 4; ++i)
#pragma unroll
        for (int r = 0; r < 4; ++r) { bd[i][r] = 3.4e38f; bi[i][r] = 0; }

    // ---- B-frag pointers; prefetch tile 0
    const _Float16* bbase = Bimg + (size_t)g * 128 + n * 8;
    half8 Bh0, Bh1, Bl0, Bl1;
    float eev;
    {
        Bh0 = *(const half8*)(bbase + 0 * 512);
        Bh1 = *(const half8*)(bbase + 1 * 512);
        Bl0 = *(const half8*)(bbase + 2 * 512);
        Bl1 = *(const half8*)(bbase + 3 * 512);
        eev = ee[n];
    }

    for (int t = 0; t < 32; ++t) {
        // prefetch next tile (wraps harmlessly to tile 0 on last iter)
        const int tn = (t + 1) & 31;
        const _Float16* bn = bbase + (size_t)tn * 2048;
        half8 Nh0 = *(const half8*)(bn + 0 * 512);
        half8 Nh1 = *(const half8*)(bn + 1 * 512);
        half8 Nl0 = *(const half8*)(bn + 2 * 512);
        half8 Nl1 = *(const half8*)(bn + 3 * 512);
        float een = ee[tn * 16 + n];

        f32x4 hh[4], cr[4];
#pragma unroll
        for (int rt = 0; rt < 4; ++rt) { hh[rt] = (f32x4){0.f, 0.f, 0.f, 0.f}; cr[rt] = (f32x4){0.f, 0.f, 0.f, 0.f}; }
#pragma unroll
        for (int rt = 0; rt < 4; ++rt) {
            hh[rt] = __builtin_amdgcn_mfma_f32_16x16x32_f16(Ahi[rt][0], Bh0, hh[rt], 0, 0, 0);
            hh[rt] = __builtin_amdgcn_mfma_f32_16x16x32_f16(Ahi[rt][1], Bh1, hh[rt], 0, 0, 0);
            cr[rt] = __builtin_amdgcn_mfma_f32_16x16x32_f16(Ahi[rt][0], Bl0, cr[rt], 0, 0, 0);
            cr[rt] = __builtin_amdgcn_mfma_f32_16x16x32_f16(Ahi[rt][1], Bl1, cr[rt], 0, 0, 0);
            cr[rt] = __builtin_amdgcn_mfma_f32_16x16x32_f16(Alo[rt][0], Bh0, cr[rt], 0, 0, 0);
            cr[rt] = __builtin_amdgcn_mfma_f32_16x16x32_f16(Alo[rt][1], Bh1, cr[rt], 0, 0, 0);
        }

        const int code = t * 16 + n;   // this lane's code column
#pragma unroll
        for (int rt = 0; rt < 4; ++rt) {
#pragma unroll
            for (int r = 0; r < 4; ++r) {
                float dot = fmaf(4.8828125e-4f, cr[rt][r], hh[rt][r]);  // hh + cross*2^-11
                float s = fmaf(-2.f, dot, eev);
                if (s < bd[rt][r]) { bd[rt][r] = s; bi[rt][r] = code; }
            }
        }

        Bh0 = Nh0; Bh1 = Nh1; Bl0 = Nl0; Bl1 = Nl1; eev = een;
    }

    // ---- cross-lane argmin over the 16 code-columns (lanes sharing l>>4 hold same rows)
#pragma unroll
    for (int mask = 1; mask < 16; mask <<= 1) {
#pragma unroll
        for (int rt = 0; rt < 4; ++rt)
#pragma unroll
            for (int r = 0; r < 4; ++r) {
                float od = __shfl_xor(bd[rt][r], mask);
                int oi = __shfl_xor(bi[rt][r], mask);
                if (od < bd[rt][r] || (od == bd[rt][r] && oi < bi[rt][r])) { bd[rt][r] = od; bi[rt][r] = oi; }
            }
    }
    if (n == 0) {
#pragma unroll
        for (int rt = 0; rt < 4; ++rt)
#pragma unroll
            for (int r = 0; r < 4; ++r)
                idx_s[w * 64 + rt * 16 + g * 4 + r] = bi[rt][r];
    }
    __syncthreads();

    // ---- epilogue: gather q, write coalesced, loss partial
    float lsum = 0.f;
#pragma unroll
    for (int p = 0; p < 4; ++p) {
        const int tok = p * 64 + (tid >> 2);
        const int part = tid & 3;
        const int gidx = idx_s[tok];
        const size_t qoff = (size_t)(bt0 + tok) * D_DIM + part * 16;
        const float4* ep = (const float4*)(ET + (size_t)gidx * D_DIM + part * 16);
        const float4* xp = (const float4*)(x + qoff);
        float4* qp = (float4*)(out_q + qoff);
#pragma unroll
        for (int u = 0; u < 4; ++u) {
            float4 qv = ep[u];
            float4 xv = xp[u];
            float dx = qv.x - xv.x, dy = qv.y - xv.y, dz = qv.z - xv.z, dw = qv.w - xv.w;
            lsum = fmaf(dx, dx, lsum);
            lsum = fmaf(dy, dy, lsum);
            lsum = fmaf(dz, dz, lsum);
            lsum = fmaf(dw, dw, lsum);
            qp[u] = qv;
        }
    }
#pragma unroll
    for (int mask = 1; mask < 64; mask <<= 1) lsum += __shfl_xor(lsum, mask);
    if (l == 0) wsum_s[w] = lsum;
    __syncthreads();
    if (tid == 0) atomicAdd(out_loss, (wsum_s[0] + wsum_s[1] + wsum_s[2] + wsum_s[3]) * loss_scale);
}

// =================== round-1 fallback (proven) ===================
#define TOK_TILE 64
#define CHUNK 64
#define NCHUNK (K_CODES / CHUNK)
#define XS_STRIDE (TOK_TILE + 4)

__global__ __launch_bounds__(256, 4) void vq_fb_main(
        const float* __restrict__ x, const float* __restrict__ E,
        float* __restrict__ out_q, float* __restrict__ out_loss, float loss_scale) {
    __shared__ __align__(16) float Xs[D_DIM][XS_STRIDE];
    __shared__ __align__(16) float Es[D_DIM][CHUNK];
    __shared__ float ee_s[K_CODES];
    __shared__ int idx_s[TOK_TILE];
    __shared__ float wsum_s[4];

    const int tid = threadIdx.x;
    const int t0 = blockIdx.x * TOK_TILE;
    const int tx = tid & 15, ty = tid >> 4;
    const int ty4 = ty * 4, tx4 = tx * 4;

#pragma unroll
    for (int it = 0; it < 4; ++it) {
        int tl = it * 16 + (tid >> 4);
        int d0 = (tid & 15) * 4;
        float4 v = *(const float4*)(x + (size_t)(t0 + tl) * D_DIM + d0);
        Xs[d0 + 0][tl] = v.x; Xs[d0 + 1][tl] = v.y; Xs[d0 + 2][tl] = v.z; Xs[d0 + 3][tl] = v.w;
    }
    for (int k = tid; k < K_CODES; k += 256) {
        float s = 0.f;
#pragma unroll
        for (int d = 0; d < D_DIM; ++d) { float v = E[(size_t)d * K_CODES + k]; s = fmaf(v, v, s); }
        ee_s[k] = s;
    }

    float bd[4] = {3.4e38f, 3.4e38f, 3.4e38f, 3.4e38f};
    int bi[4] = {0, 0, 0, 0};

    for (int c = 0; c < NCHUNK; ++c) {
        __syncthreads();
#pragma unroll
        for (int ww = 0; ww < 4; ++ww) {
            int fidx = ww * 256 + tid;
            int d = fidx >> 4, k0 = (fidx & 15) * 4;
            float4 v = *(const float4*)(E + (size_t)d * K_CODES + c * CHUNK + k0);
            *(float4*)&Es[d][k0] = v;
        }
        __syncthreads();
        float acc[4][4] = {};
#pragma unroll
        for (int d = 0; d < D_DIM; ++d) {
            float4 a = *(const float4*)&Xs[d][ty4];
            float4 b = *(const float4*)&Es[d][tx4];
            acc[0][0] = fmaf(a.x, b.x, acc[0][0]); acc[0][1] = fmaf(a.x, b.y, acc[0][1]);
            acc[0][2] = fmaf(a.x, b.z, acc[0][2]); acc[0][3] = fmaf(a.x, b.w, acc[0][3]);
            acc[1][0] = fmaf(a.y, b.x, acc[1][0]); acc[1][1] = fmaf(a.y, b.y, acc[1][1]);
            acc[1][2] = fmaf(a.y, b.z, acc[1][2]); acc[1][3] = fmaf(a.y, b.w, acc[1][3]);
            acc[2][0] = fmaf(a.z, b.x, acc[2][0]); acc[2][1] = fmaf(a.z, b.y, acc[2][1]);
            acc[2][2] = fmaf(a.z, b.z, acc[2][2]); acc[2][3] = fmaf(a.z, b.w, acc[2][3]);
            acc[3][0] = fmaf(a.w, b.x, acc[3][0]); acc[3][1] = fmaf(a.w, b.y, acc[3][1]);
            acc[3][2] = fmaf(a.w, b.z, acc[3][2]); acc[3][3] = fmaf(a.w, b.w, acc[3][3]);
        }
        const int kbase = c * CHUNK + tx4;
#pragma unroll
        for (int i = 0; i < 4; ++i)
#pragma unroll
            for (int j = 0; j < 4; ++j) {
                float s = fmaf(-2.f, acc[i][j], ee_s[kbase + j]);
                if (s < bd[i]) { bd[i] = s; bi[i] = kbase + j; }
            }
    }
#pragma unroll
    for (int mask = 1; mask < 16; mask <<= 1)
#pragma unroll
        for (int i = 0; i < 4; ++i) {
            float od = __shfl_xor(bd[i], mask);
            int oi = __shfl_xor(bi[i], mask);
            if (od < bd[i] || (od == bd[i] && oi < bi[i])) { bd[i] = od; bi[i] = oi; }
        }
    if (tx == 0)
#pragma unroll
        for (int i = 0; i < 4; ++i) idx_s[ty4 + i] = bi[i];
    __syncthreads();

    const int tok = tid >> 2, part = tid & 3;
    const int gidx = idx_s[tok];
    const int gt = t0 + tok;
    float lsum = 0.f;
#pragma unroll
    for (int ww = 0; ww < 4; ++ww) {
        int o = part * 16 + ww * 4;
        float4 qv;
        qv.x = E[(size_t)(o + 0) * K_CODES + gidx];
        qv.y = E[(size_t)(o + 1) * K_CODES + gidx];
        qv.z = E[(size_t)(o + 2) * K_CODES + gidx];
        qv.w = E[(size_t)(o + 3) * K_CODES + gidx];
        float4 xv;
        xv.x = Xs[o + 0][tok]; xv.y = Xs[o + 1][tok]; xv.z = Xs[o + 2][tok]; xv.w = Xs[o + 3][tok];
        float dx = qv.x - xv.x, dy = qv.y - xv.y, dz = qv.z - xv.z, dw = qv.w - xv.w;
        lsum = fmaf(dx, dx, lsum); lsum = fmaf(dy, dy, lsum);
        lsum = fmaf(dz, dz, lsum); lsum = fmaf(dw, dw, lsum);
        *(float4*)(out_q + (size_t)gt * D_DIM + o) = qv;
    }
#pragma unroll
    for (int mask = 1; mask < 64; mask <<= 1) lsum += __shfl_xor(lsum, mask);
    if ((tid & 63) == 0) wsum_s[tid >> 6] = lsum;
    __syncthreads();
    if (tid == 0) atomicAdd(out_loss, (wsum_s[0] + wsum_s[1] + wsum_s[2] + wsum_s[3]) * loss_scale);
}

extern "C" void kernel_launch(void* const* d_in, const int* in_sizes, int n_in,
                              void* d_out, int out_size, void* d_ws, size_t ws_size,
                              hipStream_t stream) {
    const float* x = (const float*)d_in[0];   // [B,T,D] fp32
    const float* E = (const float*)d_in[1];   // [D,K] fp32
    float* out = (float*)d_out;
    const int n_tok = in_sizes[0] / D_DIM;    // 131072
    float* loss_ptr = out + (out_size - 1);
    const float loss_scale = 2.0f / (float)(n_tok * D_DIM);

    hipMemsetAsync(loss_ptr, 0, sizeof(float), stream);

    if (ws_size >= (size_t)WS_NEEDED) {
        float* ee = (float*)((char*)d_ws + WS_EE_OFF);
        float* ET = (float*)((char*)d_ws + WS_ET_OFF);
        _Float16* Bimg = (_Float16*)((char*)d_ws + WS_BIMG_OFF);
        vq3_prep<<<2, 256, 0, stream>>>(E, ee, ET, Bimg);
        vq3_main<<<n_tok / 256, 256, 0, stream>>>(x, ee, ET, Bimg, out, loss_ptr, loss_scale);
    } else {
        vq_fb_main<<<n_tok / TOK_TILE, 256, 0, stream>>>(x, E, out, loss_ptr, loss_scale);
    }
}

// Round 3
// 127.216 us; speedup vs baseline: 1.6008x; 1.0365x over previous
//
#include <hip/hip_runtime.h>
#include <hip/hip_bf16.h>

#define D_DIM 64
#define K_CODES 512

typedef _Float16 half8 __attribute__((ext_vector_type(8)));
typedef float f32x4 __attribute__((ext_vector_type(4)));

// ws layout: ee f32[512] @0 ; ET f32[512*64] @2048 B ; Bimg f16[512*64*2] @133120 B
#define WS_EE_OFF 0
#define WS_ET_OFF 2048
#define WS_BIMG_OFF 133120
#define WS_NEEDED (133120 + 131072)

// ---------------- prep: ee, ET (gather layout), Bimg (frag-ordered f16 hi/lo) ------------
// Bimg element addr (f16 units): ((t*4 + part)*4 + g)*128 + n*8 + j
//   code k = t*16+n ; dim d = ks*32 + g*8 + j ; part: 0,1 = hi ks0/ks1 ; 2,3 = lo ks0/ks1 (lo pre-scaled by 2^11)
__global__ __launch_bounds__(256) void vq3_prep(const float* __restrict__ E,
                                                float* __restrict__ ee,
                                                float* __restrict__ ET,
                                                _Float16* __restrict__ Bimg) {
    int k = blockIdx.x * 256 + threadIdx.x;
    if (k >= K_CODES) return;
    const int t = k >> 4, n = k & 15;
    float s = 0.f;
#pragma unroll
    for (int d = 0; d < D_DIM; ++d) {
        float e = E[(size_t)d * K_CODES + k];
        s = fmaf(e, e, s);
        ET[(size_t)k * D_DIM + d] = e;
        _Float16 hi = (_Float16)e;
        _Float16 lo = (_Float16)((e - (float)hi) * 2048.0f);
        int ks = d >> 5, g = (d >> 3) & 3, j = d & 7;
        size_t base = ((size_t)(t * 4) * 4 + (size_t)g) * 128 + n * 8 + j;
        Bimg[base + (size_t)ks * 512] = hi;          // part = ks
        Bimg[base + (size_t)(2 + ks) * 512] = lo;    // part = 2+ks
    }
    ee[k] = s;
}

// ---------------- main: 3-pass split-f16 MFMA, 32 tokens/wave, grid 1024 ------------
// rt=2: tokens/wave 32, block 256 thr = 128 tokens -> 1024 blocks = 4 blocks/CU (16 waves/CU),
// 4 waves/SIMD so per-SIMD MFMA issue (~4x58 cyc) covers the ~200-cyc L2 latency of B-frag loads.
__global__ __launch_bounds__(256, 4) void vq3_main(
        const float* __restrict__ x, const float* __restrict__ ee,
        const float* __restrict__ ET, const _Float16* __restrict__ Bimg,
        float* __restrict__ out_q, float* __restrict__ out_loss, float loss_scale) {
    __shared__ int idx_s[128];
    __shared__ float wsum_s[4];

    const int tid = threadIdx.x;
    const int l = tid & 63;            // lane
    const int w = tid >> 6;            // wave in block
    const int g = l >> 4;              // k-group quad (0..3)
    const int n = l & 15;              // A row / B col within tile
    const int bt0 = blockIdx.x * 128;  // block token base
    const int t0 = bt0 + w * 32;       // wave token base (32 tokens/wave)

    // ---- A fragments: 2 row-tiles x 2 k-steps, hi and lo(x2^11), held in regs all kernel
    half8 Ahi[2][2], Alo[2][2];
#pragma unroll
    for (int rt = 0; rt < 2; ++rt) {
#pragma unroll
        for (int ks = 0; ks < 2; ++ks) {
            const float4* xp = (const float4*)(x + (size_t)(t0 + rt * 16 + n) * D_DIM + ks * 32 + g * 8);
            float4 a = xp[0], b = xp[1];
            float va[8] = {a.x, a.y, a.z, a.w, b.x, b.y, b.z, b.w};
            half8 h, lo;
#pragma unroll
            for (int j = 0; j < 8; ++j) {
                _Float16 hj = (_Float16)va[j];
                h[j] = hj;
                lo[j] = (_Float16)((va[j] - (float)hj) * 2048.0f);
            }
            Ahi[rt][ks] = h;
            Alo[rt][ks] = lo;
        }
    }

    // ---- running argmin state
    float bd[2][4];
    int bi[2][4];
#pragma unroll
    for (int i = 0; i < 2; ++i)
#pragma unroll
        for (int r = 0; r < 4; ++r) { bd[i][r] = 3.4e38f; bi[i][r] = 0; }

    // ---- B-frag pointers; prefetch tile 0
    const _Float16* bbase = Bimg + (size_t)g * 128 + n * 8;
    half8 Bh0, Bh1, Bl0, Bl1;
    float eev;
    {
        Bh0 = *(const half8*)(bbase + 0 * 512);
        Bh1 = *(const half8*)(bbase + 1 * 512);
        Bl0 = *(const half8*)(bbase + 2 * 512);
        Bl1 = *(const half8*)(bbase + 3 * 512);
        eev = ee[n];
    }

#pragma unroll 2
    for (int t = 0; t < 32; ++t) {
        // prefetch next tile (wraps harmlessly to tile 0 on last iter)
        const int tn = (t + 1) & 31;
        const _Float16* bn = bbase + (size_t)tn * 2048;
        half8 Nh0 = *(const half8*)(bn + 0 * 512);
        half8 Nh1 = *(const half8*)(bn + 1 * 512);
        half8 Nl0 = *(const half8*)(bn + 2 * 512);
        half8 Nl1 = *(const half8*)(bn + 3 * 512);
        float een = ee[tn * 16 + n];

        f32x4 hh[2], cr[2];
#pragma unroll
        for (int rt = 0; rt < 2; ++rt) { hh[rt] = (f32x4){0.f, 0.f, 0.f, 0.f}; cr[rt] = (f32x4){0.f, 0.f, 0.f, 0.f}; }
#pragma unroll
        for (int rt = 0; rt < 2; ++rt) {
            hh[rt] = __builtin_amdgcn_mfma_f32_16x16x32_f16(Ahi[rt][0], Bh0, hh[rt], 0, 0, 0);
            hh[rt] = __builtin_amdgcn_mfma_f32_16x16x32_f16(Ahi[rt][1], Bh1, hh[rt], 0, 0, 0);
            cr[rt] = __builtin_amdgcn_mfma_f32_16x16x32_f16(Ahi[rt][0], Bl0, cr[rt], 0, 0, 0);
            cr[rt] = __builtin_amdgcn_mfma_f32_16x16x32_f16(Ahi[rt][1], Bl1, cr[rt], 0, 0, 0);
            cr[rt] = __builtin_amdgcn_mfma_f32_16x16x32_f16(Alo[rt][0], Bh0, cr[rt], 0, 0, 0);
            cr[rt] = __builtin_amdgcn_mfma_f32_16x16x32_f16(Alo[rt][1], Bh1, cr[rt], 0, 0, 0);
        }

        const int code = t * 16 + n;   // this lane's code column
#pragma unroll
        for (int rt = 0; rt < 2; ++rt) {
#pragma unroll
            for (int r = 0; r < 4; ++r) {
                float dot = fmaf(4.8828125e-4f, cr[rt][r], hh[rt][r]);  // hh + cross*2^-11
                float s = fmaf(-2.f, dot, eev);
                if (s < bd[rt][r]) { bd[rt][r] = s; bi[rt][r] = code; }
            }
        }

        Bh0 = Nh0; Bh1 = Nh1; Bl0 = Nl0; Bl1 = Nl1; eev = een;
    }

    // ---- cross-lane argmin over the 16 code-columns (reduce over lane bits 0..3)
#pragma unroll
    for (int mask = 1; mask < 16; mask <<= 1) {
#pragma unroll
        for (int rt = 0; rt < 2; ++rt)
#pragma unroll
            for (int r = 0; r < 4; ++r) {
                float od = __shfl_xor(bd[rt][r], mask);
                int oi = __shfl_xor(bi[rt][r], mask);
                if (od < bd[rt][r] || (od == bd[rt][r] && oi < bi[rt][r])) { bd[rt][r] = od; bi[rt][r] = oi; }
            }
    }
    if (n == 0) {
#pragma unroll
        for (int rt = 0; rt < 2; ++rt)
#pragma unroll
            for (int r = 0; r < 4; ++r)
                idx_s[w * 32 + rt * 16 + g * 4 + r] = bi[rt][r];   // C-layout: row = g*4 + r
    }
    __syncthreads();

    // ---- epilogue: gather q, write coalesced, loss partial
    float lsum = 0.f;
#pragma unroll
    for (int p = 0; p < 2; ++p) {
        const int tok = p * 64 + (tid >> 2);
        const int part = tid & 3;
        const int gidx = idx_s[tok];
        const size_t qoff = (size_t)(bt0 + tok) * D_DIM + part * 16;
        const float4* ep = (const float4*)(ET + (size_t)gidx * D_DIM + part * 16);
        const float4* xp = (const float4*)(x + qoff);
        float4* qp = (float4*)(out_q + qoff);
#pragma unroll
        for (int u = 0; u < 4; ++u) {
            float4 qv = ep[u];
            float4 xv = xp[u];
            float dx = qv.x - xv.x, dy = qv.y - xv.y, dz = qv.z - xv.z, dw = qv.w - xv.w;
            lsum = fmaf(dx, dx, lsum);
            lsum = fmaf(dy, dy, lsum);
            lsum = fmaf(dz, dz, lsum);
            lsum = fmaf(dw, dw, lsum);
            qp[u] = qv;
        }
    }
#pragma unroll
    for (int mask = 1; mask < 64; mask <<= 1) lsum += __shfl_xor(lsum, mask);
    if (l == 0) wsum_s[w] = lsum;
    __syncthreads();
    if (tid == 0) atomicAdd(out_loss, (wsum_s[0] + wsum_s[1] + wsum_s[2] + wsum_s[3]) * loss_scale);
}

// =================== round-1 fallback (proven) ===================
#define TOK_TILE 64
#define CHUNK 64
#define NCHUNK (K_CODES / CHUNK)
#define XS_STRIDE (TOK_TILE + 4)

__global__ __launch_bounds__(256, 4) void vq_fb_main(
        const float* __restrict__ x, const float* __restrict__ E,
        float* __restrict__ out_q, float* __restrict__ out_loss, float loss_scale) {
    __shared__ __align__(16) float Xs[D_DIM][XS_STRIDE];
    __shared__ __align__(16) float Es[D_DIM][CHUNK];
    __shared__ float ee_s[K_CODES];
    __shared__ int idx_s[TOK_TILE];
    __shared__ float wsum_s[4];

    const int tid = threadIdx.x;
    const int t0 = blockIdx.x * TOK_TILE;
    const int tx = tid & 15, ty = tid >> 4;
    const int ty4 = ty * 4, tx4 = tx * 4;

#pragma unroll
    for (int it = 0; it < 4; ++it) {
        int tl = it * 16 + (tid >> 4);
        int d0 = (tid & 15) * 4;
        float4 v = *(const float4*)(x + (size_t)(t0 + tl) * D_DIM + d0);
        Xs[d0 + 0][tl] = v.x; Xs[d0 + 1][tl] = v.y; Xs[d0 + 2][tl] = v.z; Xs[d0 + 3][tl] = v.w;
    }
    for (int k = tid; k < K_CODES; k += 256) {
        float s = 0.f;
#pragma unroll
        for (int d = 0; d < D_DIM; ++d) { float v = E[(size_t)d * K_CODES + k]; s = fmaf(v, v, s); }
        ee_s[k] = s;
    }

    float bd[4] = {3.4e38f, 3.4e38f, 3.4e38f, 3.4e38f};
    int bi[4] = {0, 0, 0, 0};

    for (int c = 0; c < NCHUNK; ++c) {
        __syncthreads();
#pragma unroll
        for (int ww = 0; ww < 4; ++ww) {
            int fidx = ww * 256 + tid;
            int d = fidx >> 4, k0 = (fidx & 15) * 4;
            float4 v = *(const float4*)(E + (size_t)d * K_CODES + c * CHUNK + k0);
            *(float4*)&Es[d][k0] = v;
        }
        __syncthreads();
        float acc[4][4] = {};
#pragma unroll
        for (int d = 0; d < D_DIM; ++d) {
            float4 a = *(const float4*)&Xs[d][ty4];
            float4 b = *(const float4*)&Es[d][tx4];
            acc[0][0] = fmaf(a.x, b.x, acc[0][0]); acc[0][1] = fmaf(a.x, b.y, acc[0][1]);
            acc[0][2] = fmaf(a.x, b.z, acc[0][2]); acc[0][3] = fmaf(a.x, b.w, acc[0][3]);
            acc[1][0] = fmaf(a.y, b.x, acc[1][0]); acc[1][1] = fmaf(a.y, b.y, acc[1][1]);
            acc[1][2] = fmaf(a.y, b.z, acc[1][2]); acc[1][3] = fmaf(a.y, b.w, acc[1][3]);
            acc[2][0] = fmaf(a.z, b.x, acc[2][0]); acc[2][1] = fmaf(a.z, b.y, acc[2][1]);
            acc[2][2] = fmaf(a.z, b.z, acc[2][2]); acc[2][3] = fmaf(a.z, b.w, acc[2][3]);
            acc[3][0] = fmaf(a.w, b.x, acc[3][0]); acc[3][1] = fmaf(a.w, b.y, acc[3][1]);
            acc[3][2] = fmaf(a.w, b.z, acc[3][2]); acc[3][3] = fmaf(a.w, b.w, acc[3][3]);
        }
        const int kbase = c * CHUNK + tx4;
#pragma unroll
        for (int i = 0; i < 4; ++i)
#pragma unroll
            for (int j = 0; j < 4; ++j) {
                float s = fmaf(-2.f, acc[i][j], ee_s[kbase + j]);
                if (s < bd[i]) { bd[i] = s; bi[i] = kbase + j; }
            }
    }
#pragma unroll
    for (int mask = 1; mask < 16; mask <<= 1)
#pragma unroll
        for (int i = 0; i < 4; ++i) {
            float od = __shfl_xor(bd[i], mask);
            int oi = __shfl_xor(bi[i], mask);
            if (od < bd[i] || (od == bd[i] && oi < bi[i])) { bd[i] = od; bi[i] = oi; }
        }
    if (tx == 0)
#pragma unroll
        for (int i = 0; i < 4; ++i) idx_s[ty4 + i] = bi[i];
    __syncthreads();

    const int tok = tid >> 2, part = tid & 3;
    const int gidx = idx_s[tok];
    const int gt = t0 + tok;
    float lsum = 0.f;
#pragma unroll
    for (int ww = 0; ww < 4; ++ww) {
        int o = part * 16 + ww * 4;
        float4 qv;
        qv.x = E[(size_t)(o + 0) * K_CODES + gidx];
        qv.y = E[(size_t)(o + 1) * K_CODES + gidx];
        qv.z = E[(size_t)(o + 2) * K_CODES + gidx];
        qv.w = E[(size_t)(o + 3) * K_CODES + gidx];
        float4 xv;
        xv.x = Xs[o + 0][tok]; xv.y = Xs[o + 1][tok]; xv.z = Xs[o + 2][tok]; xv.w = Xs[o + 3][tok];
        float dx = qv.x - xv.x, dy = qv.y - xv.y, dz = qv.z - xv.z, dw = qv.w - xv.w;
        lsum = fmaf(dx, dx, lsum); lsum = fmaf(dy, dy, lsum);
        lsum = fmaf(dz, dz, lsum); lsum = fmaf(dw, dw, lsum);
        *(float4*)(out_q + (size_t)gt * D_DIM + o) = qv;
    }
#pragma unroll
    for (int mask = 1; mask < 64; mask <<= 1) lsum += __shfl_xor(lsum, mask);
    if ((tid & 63) == 0) wsum_s[tid >> 6] = lsum;
    __syncthreads();
    if (tid == 0) atomicAdd(out_loss, (wsum_s[0] + wsum_s[1] + wsum_s[2] + wsum_s[3]) * loss_scale);
}

extern "C" void kernel_launch(void* const* d_in, const int* in_sizes, int n_in,
                              void* d_out, int out_size, void* d_ws, size_t ws_size,
                              hipStream_t stream) {
    const float* x = (const float*)d_in[0];   // [B,T,D] fp32
    const float* E = (const float*)d_in[1];   // [D,K] fp32
    float* out = (float*)d_out;
    const int n_tok = in_sizes[0] / D_DIM;    // 131072
    float* loss_ptr = out + (out_size - 1);
    const float loss_scale = 2.0f / (float)(n_tok * D_DIM);

    hipMemsetAsync(loss_ptr, 0, sizeof(float), stream);

    if (ws_size >= (size_t)WS_NEEDED) {
        float* ee = (float*)((char*)d_ws + WS_EE_OFF);
        float* ET = (float*)((char*)d_ws + WS_ET_OFF);
        _Float16* Bimg = (_Float16*)((char*)d_ws + WS_BIMG_OFF);
        vq3_prep<<<2, 256, 0, stream>>>(E, ee, ET, Bimg);
        vq3_main<<<n_tok / 128, 256, 0, stream>>>(x, ee, ET, Bimg, out, loss_ptr, loss_scale);
    } else {
        vq_fb_main<<<n_tok / TOK_TILE, 256, 0, stream>>>(x, E, out, loss_ptr, loss_scale);
    }
}